// Round 1
// 3902.854 us; speedup vs baseline: 1.8894x; 1.8894x over previous
//
#include <hip/hip_runtime.h>

typedef unsigned short u16;
typedef unsigned int   u32;
typedef short s16x8 __attribute__((ext_vector_type(8)));   // 8 bf16 lanes for MFMA
typedef float f32x4 __attribute__((ext_vector_type(4)));

// ---- bf16 helpers (store with round-to-nearest-even) ----
static __device__ __forceinline__ float bf2f(u16 v){ return __uint_as_float(((u32)v)<<16); }
static __device__ __forceinline__ u16 f2bf(float f){
  u32 u = __float_as_uint(f);
  u32 r = (u + 0x7fffu + ((u>>16)&1u)) >> 16;
  return (u16)r;
}
static __device__ __forceinline__ float cvt(float v){ return v; }
static __device__ __forceinline__ float cvt(u16 v){ return bf2f(v); }
static __device__ __forceinline__ void stv(float* p, float v){ *p = v; }
static __device__ __forceinline__ void stv(u16* p, float v){ *p = f2bf(v); }

static __device__ __forceinline__ void ld2(const float* p, float& a, float& b){
  float2 t = *(const float2*)p; a=t.x; b=t.y;
}
static __device__ __forceinline__ void ld2(const u16* p, float& a, float& b){
  u32 t = *(const u32*)p; a = __uint_as_float(t<<16); b = __uint_as_float(t & 0xffff0000u);
}
static __device__ __forceinline__ void st2(float* p, float a, float b){
  float2 t; t.x=a; t.y=b; *(float2*)p = t;
}
static __device__ __forceinline__ void st2(u16* p, float a, float b){
  *(u32*)p = ((u32)f2bf(a)) | (((u32)f2bf(b))<<16);
}

// ---------------- RMSNorm: O = X / rms(X) * scale, vectorized 2-wide ----------------
template<typename TI, typename TO>
__global__ __launch_bounds__(256) void rms_k(const TI* __restrict__ X,
                                             const float* __restrict__ scale,
                                             TO* __restrict__ O)
{
  int row = blockIdx.x*4 + (threadIdx.x>>6);
  int lane = threadIdx.x&63;
  const TI* xr = X + (size_t)row*384;
  float v[6]; float ss = 0.f;
#pragma unroll
  for(int i=0;i<3;i++){
    ld2(xr + 2*lane + 128*i, v[2*i], v[2*i+1]);
    ss += v[2*i]*v[2*i] + v[2*i+1]*v[2*i+1];
  }
#pragma unroll
  for(int off=32; off>0; off>>=1) ss += __shfl_down(ss, off, 64);
  ss = __shfl(ss, 0, 64);
  float r = rsqrtf(ss*(1.0f/384.0f)+1e-6f);
  TO* orow = O + (size_t)row*384;
#pragma unroll
  for(int i=0;i<3;i++){
    int c = 2*lane + 128*i;
    st2(orow + c, v[2*i]*r*scale[c], v[2*i+1]*r*scale[c+1]);
  }
}

// ---------------- transpose + cast fp32 -> bf16: Out[c][r] = (r<Rr ? In[r][c] : 0) ----------------
__global__ __launch_bounds__(256) void tcast_k(const float* __restrict__ In, long isz,
                                               u16* __restrict__ Out, long osz,
                                               int Rr, int Cc, int ldo)
{
  __shared__ float t[32][33];
  const int z = blockIdx.z;
  const float* I = In + (long)z*isz;
  u16* Oz = Out + (long)z*osz;
  const int r0 = blockIdx.x*32, c0 = blockIdx.y*32;
  const int tx = threadIdx.x&31, ty = threadIdx.x>>5;
#pragma unroll
  for(int rr=ty; rr<32; rr+=8){
    int r = r0+rr, c = c0+tx;
    t[rr][tx] = (r<Rr && c<Cc) ? I[(size_t)r*Cc + c] : 0.f;
  }
  __syncthreads();
#pragma unroll
  for(int cc=ty; cc<32; cc+=8){
    int c = c0+cc, r = r0+tx;
    if(c<Cc && r<ldo) Oz[(size_t)c*ldo + r] = f2bf(t[tx][cc]);
  }
}

// ---------------- bf16 MFMA GEMM: C = A[M,K] @ Bt[N,K]^T (+ beta*R + bias, relu) ----------------
// 128x64 tile, BK=32, 4 waves (2x2), 16x16x32 bf16 MFMA, fp32 accum.
// LDS rows padded to 40 u16 (80 B = 5x16B) -> conflict-free ds_read_b128 fragments.
// C/R offset = (m>>8)*cs_hi + (m&255)*cs_lo + z*{csz,rsz} + n  (handles QKV scatter)
// n in [N,Nstore) writes zeros (used to zero-pad h5 columns 307..319).
template<typename TC, typename TR>
__global__ __launch_bounds__(256,4) void mgemm_k(
    const u16* __restrict__ A, int lda, long asz,
    const u16* __restrict__ Bt, int ldb, long bsz,
    TC* __restrict__ C, long csz, long cs_hi, int cs_lo,
    const TR* __restrict__ R, long rsz,
    const float* __restrict__ bias,
    int M, int N, int Nstore, int K, float beta, int relu)
{
  __shared__ __align__(16) u16 As[128*40];
  __shared__ __align__(16) u16 Bs[64*40];
  const int z = blockIdx.z;
  const u16* Az = A + (long)z*asz;
  const u16* Bz = Bt + (long)z*bsz;
  const int m0 = blockIdx.x*128, n0 = blockIdx.y*64;
  const int tid = threadIdx.x;
  const int w = tid>>6, lane = tid&63;
  const int g4 = lane>>4, l16 = lane&15;
  const int wr = w>>1, wc = w&1;
  const int arow = tid>>2, akc = (tid&3)*8;

  const u16* gA0 = Az + (size_t)(m0+arow)*lda + akc;
  const u16* gA1 = Az + (size_t)(m0+64+arow)*lda + akc;
  const bool bok = (n0 + arow) < N;
  const u16* gB  = Bz + (size_t)(bok ? (n0+arow) : 0)*ldb + akc;
  uint4* dA0 = (uint4*)&As[arow*40 + akc];
  uint4* dA1 = (uint4*)&As[(64+arow)*40 + akc];
  uint4* dB  = (uint4*)&Bs[arow*40 + akc];
  if(!bok){ *dB = make_uint4(0,0,0,0); }

  f32x4 fz = {0.f,0.f,0.f,0.f};
  f32x4 acc[4][2];
#pragma unroll
  for(int i=0;i<4;i++)
#pragma unroll
    for(int j=0;j<2;j++) acc[i][j]=fz;

  for(int k0=0;k0<K;k0+=32){
    *dA0 = *(const uint4*)gA0;  gA0 += 32;
    *dA1 = *(const uint4*)gA1;  gA1 += 32;
    if(bok){ *dB = *(const uint4*)gB; gB += 32; }
    __syncthreads();
    s16x8 av[4], bv[2];
#pragma unroll
    for(int mf=0;mf<4;mf++)
      av[mf] = *(const s16x8*)&As[(wr*64 + mf*16 + l16)*40 + g4*8];
#pragma unroll
    for(int nf=0;nf<2;nf++)
      bv[nf] = *(const s16x8*)&Bs[(wc*32 + nf*16 + l16)*40 + g4*8];
#pragma unroll
    for(int mf=0;mf<4;mf++)
#pragma unroll
      for(int nf=0;nf<2;nf++)
        acc[mf][nf] = __builtin_amdgcn_mfma_f32_16x16x32_bf16(av[mf], bv[nf], acc[mf][nf], 0,0,0);
    __syncthreads();
  }
  // epilogue: D layout col=lane&15, row=(lane>>4)*4+i
#pragma unroll
  for(int mf=0;mf<4;mf++)
#pragma unroll
    for(int i=0;i<4;i++){
      int m = m0 + wr*64 + mf*16 + g4*4 + i;
      long rowoff = (long)(m>>8)*cs_hi + (long)(m&255)*cs_lo;
#pragma unroll
      for(int nf=0;nf<2;nf++){
        int n = n0 + wc*32 + nf*16 + l16;
        if(n < Nstore){
          float v = 0.f;
          if(n < N){
            v = acc[mf][nf][i];
            if(R)    v += beta*cvt(R[rowoff + (long)z*rsz + n]);
            if(bias) v += bias[n];
            if(relu) v  = fmaxf(v, 0.f);
          }
          stv(C + (long)z*csz + rowoff + n, v);
        }
      }
    }
}

// ---------------- MFMA causal flash attention: one block per (b,h), T=256, HS=64 ----------------
// 4 waves, wave w owns Q rows [64w,64w+64). KV tiles of 64 staged to LDS (XOR-swizzled).
// QK^T computed swapped (A=K, B=Q) so D[s][m] has m = lane&15 -> per-lane row-local softmax.
// P -> wave-private swizzled LDS -> A-fragments for PV; V staged transposed for B-fragments.
__global__ __launch_bounds__(256,2) void mattn_k(const u16* __restrict__ Q,
                                                 const u16* __restrict__ Kg,
                                                 const u16* __restrict__ Vg,
                                                 u16* __restrict__ O)
{
  __shared__ __align__(16) u16 Ks[64*64];    // [s][d], byte = s*128+2d ^ ((s&7)<<4)
  __shared__ __align__(16) u16 Vts[64*64];   // [d][s], byte = d*128+2s ^ ((d&7)<<4)
  __shared__ __align__(16) u16 Ps[4*4096];   // per-wave [m][s], byte = m*128+2s ^ ((m&7)<<4)
  const int bh = blockIdx.x;
  const int b = bh/6, h = bh - b*6;
  const u16* Qb = Q  + (size_t)bh*16384;
  const u16* Kb = Kg + (size_t)bh*16384;
  const u16* Vb = Vg + (size_t)bh*16384;
  const int tid = threadIdx.x;
  const int w = tid>>6, lane = tid&63;
  const int g4 = lane>>4, l16 = lane&15;
  char* PB = (char*)&Ps[w*4096];
  const int swz = (l16&7)<<4;

  // Q fragments (B-operand): lane holds Q[m=l16+16mi][d=ks*32+g4*8+j]
  s16x8 qf[4][2];
#pragma unroll
  for(int mi=0;mi<4;mi++)
#pragma unroll
    for(int ks=0;ks<2;ks++)
      qf[mi][ks] = *(const s16x8*)(Qb + (size_t)(w*64 + mi*16 + l16)*64 + ks*32 + g4*8);

  f32x4 fzv = {0.f,0.f,0.f,0.f};
  f32x4 o[4][4];
#pragma unroll
  for(int mf=0;mf<4;mf++)
#pragma unroll
    for(int df=0;df<4;df++) o[mf][df]=fzv;
  float mrun[4], lrun[4];
#pragma unroll
  for(int mi=0;mi<4;mi++){ mrun[mi]=-1e30f; lrun[mi]=0.f; }

  for(int st=0; st<4; ++st){
    if(st) __syncthreads();            // previous tile fully consumed before restage
    // stage K tile (coalesced 16B, b128 LDS writes)
#pragma unroll
    for(int it=0; it<2; ++it){
      int c = tid + 256*it;
      int s = c>>3, d0 = (c&7)*8;
      uint4 ld = *(const uint4*)(Kb + (size_t)(st*64+s)*64 + d0);
      int byte = s*128 + d0*2; byte ^= (s&7)<<4;
      *(uint4*)((char*)Ks + byte) = ld;
    }
    // stage V^T tile (s-major lane map -> conflict-free scalar writes; L1/L2 absorb reads)
#pragma unroll
    for(int it=0; it<2; ++it){
      int c = tid + 256*it;
      int s = c&63, d0 = (c>>6)*8;
      uint4 ld = *(const uint4*)(Vb + (size_t)(st*64+s)*64 + d0);
#pragma unroll
      for(int jj=0; jj<4; ++jj){
        u32 ww = (jj==0)?ld.x:(jj==1)?ld.y:(jj==2)?ld.z:ld.w;
        int d = d0 + 2*jj;
        int byte0 = d*128 + s*2;     byte0 ^= (d&7)<<4;
        int byte1 = (d+1)*128 + s*2; byte1 ^= ((d+1)&7)<<4;
        *(u16*)((char*)Vts + byte0) = (u16)(ww & 0xffffu);
        *(u16*)((char*)Vts + byte1) = (u16)(ww >> 16);
      }
    }
    __syncthreads();
    if(w < st) continue;               // wave-uniform causal tile skip

    // S^T = K . Q^T : D[s][m], frags sc[sf][mi]
    f32x4 sc[4][4];
#pragma unroll
    for(int sf=0; sf<4; ++sf){
      int row = sf*16 + l16;
      s16x8 kf0 = *(const s16x8*)((char*)Ks + ((row*128 + g4*16) ^ swz));
      s16x8 kf1 = *(const s16x8*)((char*)Ks + ((row*128 + 64 + g4*16) ^ swz));
#pragma unroll
      for(int mi=0; mi<4; ++mi){
        f32x4 t = __builtin_amdgcn_mfma_f32_16x16x32_bf16(kf0, qf[mi][0], fzv, 0,0,0);
        sc[sf][mi] = __builtin_amdgcn_mfma_f32_16x16x32_bf16(kf1, qf[mi][1], t, 0,0,0);
      }
    }
    // online softmax per row m = mi*16+l16; row spread over lanes l16+16*g4'
    float alpha[4];
#pragma unroll
    for(int mi=0; mi<4; ++mi){
      int mloc = mi*16 + l16;
      float rmax = -3.0e38f;
#pragma unroll
      for(int sf=0; sf<4; ++sf)
#pragma unroll
        for(int i=0;i<4;i++){
          float vv = sc[sf][mi][i]*0.125f;
          if(st==w && (sf*16 + g4*4 + i) > mloc) vv = -1e30f;
          sc[sf][mi][i] = vv;
          rmax = fmaxf(rmax, vv);
        }
      rmax = fmaxf(rmax, __shfl_xor(rmax, 16, 64));
      rmax = fmaxf(rmax, __shfl_xor(rmax, 32, 64));
      float mnew = fmaxf(mrun[mi], rmax);
      float al = __expf(mrun[mi] - mnew);
      mrun[mi] = mnew;
      float ls = 0.f;
#pragma unroll
      for(int sf=0; sf<4; ++sf){
        float p0 = __expf(sc[sf][mi][0]-mnew);
        float p1 = __expf(sc[sf][mi][1]-mnew);
        float p2 = __expf(sc[sf][mi][2]-mnew);
        float p3 = __expf(sc[sf][mi][3]-mnew);
        ls += p0+p1+p2+p3;
        ushort4 pk; pk.x=f2bf(p0); pk.y=f2bf(p1); pk.z=f2bf(p2); pk.w=f2bf(p3);
        int byte = mloc*128 + sf*32 + g4*8; byte ^= (l16&7)<<4;
        *(ushort4*)(PB + byte) = pk;
      }
      ls += __shfl_xor(ls, 16, 64);
      ls += __shfl_xor(ls, 32, 64);
      lrun[mi] = lrun[mi]*al + ls;
      alpha[mi] = al;
    }
    // rescale O (stats live at lanes 0..15; O rows are (g4*4+i))
#pragma unroll
    for(int mf=0; mf<4; ++mf)
#pragma unroll
      for(int i=0;i<4;i++){
        float at = __shfl(alpha[mf], g4*4 + i, 64);
#pragma unroll
        for(int df=0; df<4; ++df) o[mf][df][i] *= at;
      }
    // PV: O[m][d] += P[m][s] V[s][d]
    s16x8 vbf[4][2];
#pragma unroll
    for(int df=0; df<4; ++df){
      int row = df*16 + l16;
      vbf[df][0] = *(const s16x8*)((char*)Vts + ((row*128 + g4*16) ^ swz));
      vbf[df][1] = *(const s16x8*)((char*)Vts + ((row*128 + 64 + g4*16) ^ swz));
    }
#pragma unroll
    for(int mf=0; mf<4; ++mf){
      int row = mf*16 + l16;
      s16x8 pa0 = *(const s16x8*)(PB + ((row*128 + g4*16) ^ swz));
      s16x8 pa1 = *(const s16x8*)(PB + ((row*128 + 64 + g4*16) ^ swz));
#pragma unroll
      for(int df=0; df<4; ++df){
        f32x4 t = __builtin_amdgcn_mfma_f32_16x16x32_bf16(pa0, vbf[df][0], o[mf][df], 0,0,0);
        o[mf][df] = __builtin_amdgcn_mfma_f32_16x16x32_bf16(pa1, vbf[df][1], t, 0,0,0);
      }
    }
  }
  // normalize + store bf16 to attn_cat[b][t][h*64+d]
#pragma unroll
  for(int mf=0; mf<4; ++mf)
#pragma unroll
    for(int i=0;i<4;i++){
      float lt = __shfl(lrun[mf], g4*4 + i, 64);
      float rl = 1.f/lt;
      u16* orow = O + ((size_t)(b*256 + w*64 + mf*16 + g4*4 + i))*384 + h*64;
#pragma unroll
      for(int df=0; df<4; ++df)
        orow[df*16 + l16] = f2bf(o[mf][df][i]*rl);
    }
}

// ---------------- fp32 VALU GEMM (kept ONLY for the Newton-Schulz orth loop) ----------------
template<typename TA, typename TB, typename TC, typename TR>
__global__ __launch_bounds__(256) void gemm_k(
    const TA* __restrict__ A, int lda, long asz,
    const TB* __restrict__ B, int ldb, long bsz,
    TC* __restrict__ C, long csz, long cs_hi, int cs_lo,
    const TR* __restrict__ R, long rsz,
    const float* __restrict__ bias,
    int M, int N, int K, float alpha, float beta, int relu)
{
  __shared__ __align__(16) float As[16][68];
  __shared__ __align__(16) float Bs[16][68];
  const int z = blockIdx.z;
  const TA* Az = A + (long)z*asz;
  const TB* Bz = B + (long)z*bsz;
  const int m0 = blockIdx.x*64, n0 = blockIdx.y*64;
  const int tid = threadIdx.x;
  const int tm = tid>>4, tn = tid&15;
  const int la_m = tid>>4, la_k = tid&15;
  const int lb_k = tid>>6, lb_n = tid&63;
  float acc[4][4];
#pragma unroll
  for(int i=0;i<4;i++)
#pragma unroll
    for(int j=0;j<4;j++) acc[i][j]=0.f;

  for(int k0=0;k0<K;k0+=16){
#pragma unroll
    for(int i=0;i<4;i++){
      int m = m0 + la_m + 16*i;
      int kk = k0 + la_k;
      As[la_k][la_m+16*i] = (kk<K) ? cvt(Az[(size_t)m*lda + kk]) : 0.f;
    }
#pragma unroll
    for(int i=0;i<4;i++){
      int kk = k0 + lb_k + 4*i;
      int n  = n0 + lb_n;
      Bs[lb_k+4*i][lb_n] = (kk<K && n<N) ? cvt(Bz[(size_t)kk*ldb + n]) : 0.f;
    }
    __syncthreads();
#pragma unroll
    for(int kk=0;kk<16;kk++){
      float4 av = *(const float4*)&As[kk][tm*4];
      float4 bv = *(const float4*)&Bs[kk][tn*4];
      acc[0][0]+=av.x*bv.x; acc[0][1]+=av.x*bv.y; acc[0][2]+=av.x*bv.z; acc[0][3]+=av.x*bv.w;
      acc[1][0]+=av.y*bv.x; acc[1][1]+=av.y*bv.y; acc[1][2]+=av.y*bv.z; acc[1][3]+=av.y*bv.w;
      acc[2][0]+=av.z*bv.x; acc[2][1]+=av.z*bv.y; acc[2][2]+=av.z*bv.z; acc[2][3]+=av.z*bv.w;
      acc[3][0]+=av.w*bv.x; acc[3][1]+=av.w*bv.y; acc[3][2]+=av.w*bv.z; acc[3][3]+=av.w*bv.w;
    }
    __syncthreads();
  }
#pragma unroll
  for(int i=0;i<4;i++){
    int m = m0 + tm*4 + i;
    long rowoff = (long)(m>>8)*cs_hi + (long)(m&255)*cs_lo;
#pragma unroll
    for(int j=0;j<4;j++){
      int n = n0 + tn*4 + j;
      if(n<N){
        float v = alpha*acc[i][j];
        if(R)    v += beta*cvt(R[rowoff + (long)z*rsz + n]);
        if(bias) v += bias[n];
        if(relu) v  = fmaxf(v, 0.f);
        stv(C + (long)z*csz + rowoff + n, v);
      }
    }
  }
}

// ---------------- Gram: G = X^T X for 384x384 fp32, batched z (NS loop) ----------------
__global__ __launch_bounds__(256) void gram_k(const float* __restrict__ X, long xsz,
                                              float* __restrict__ G, long gsz)
{
  __shared__ __align__(16) float As[16][68];
  __shared__ __align__(16) float Bs[16][68];
  const int z = blockIdx.z;
  const float* Xz = X + (long)z*xsz;
  float* Gz = G + (long)z*gsz;
  const int i0 = blockIdx.x*64, j0 = blockIdx.y*64;
  const int tid = threadIdx.x;
  const int tm = tid>>4, tn = tid&15;
  const int lr = tid>>6, lc = tid&63;
  float acc[4][4];
#pragma unroll
  for(int i=0;i<4;i++)
#pragma unroll
    for(int j=0;j<4;j++) acc[i][j]=0.f;

  for(int c0=0;c0<384;c0+=16){
#pragma unroll
    for(int i=0;i<4;i++){
      int c = c0 + lr + 4*i;
      As[lr+4*i][lc] = Xz[(size_t)c*384 + i0 + lc];
      Bs[lr+4*i][lc] = Xz[(size_t)c*384 + j0 + lc];
    }
    __syncthreads();
#pragma unroll
    for(int kk=0;kk<16;kk++){
      float4 av = *(const float4*)&As[kk][tm*4];
      float4 bv = *(const float4*)&Bs[kk][tn*4];
      acc[0][0]+=av.x*bv.x; acc[0][1]+=av.x*bv.y; acc[0][2]+=av.x*bv.z; acc[0][3]+=av.x*bv.w;
      acc[1][0]+=av.y*bv.x; acc[1][1]+=av.y*bv.y; acc[1][2]+=av.y*bv.z; acc[1][3]+=av.y*bv.w;
      acc[2][0]+=av.z*bv.x; acc[2][1]+=av.z*bv.y; acc[2][2]+=av.z*bv.z; acc[2][3]+=av.z*bv.w;
      acc[3][0]+=av.w*bv.x; acc[3][1]+=av.w*bv.y; acc[3][2]+=av.w*bv.z; acc[3][3]+=av.w*bv.w;
    }
    __syncthreads();
  }
#pragma unroll
  for(int i=0;i<4;i++)
#pragma unroll
    for(int j=0;j<4;j++)
      Gz[(size_t)(i0+tm*4+i)*384 + j0+tn*4+j] = acc[i][j];
}

// ---------------- Frobenius norm (inverse) of the two fp32 Wo matrices ----------------
__global__ __launch_bounds__(256) void fnorm_k(const float* __restrict__ W0,
                                               const float* __restrict__ W1,
                                               float* __restrict__ inv)
{
  const float* W = blockIdx.x ? W1 : W0;
  int tid = threadIdx.x;
  float s=0.f;
  for(int i=tid;i<147456;i+=256){ float v=W[i]; s+=v*v; }
  __shared__ float red[256];
  red[tid]=s; __syncthreads();
  for(int off=128;off>0;off>>=1){
    if(tid<off) red[tid]+=red[tid+off];
    __syncthreads();
  }
  if(tid==0) inv[blockIdx.x] = rsqrtf(red[0]);
}

__global__ __launch_bounds__(256) void nsinit_k(const float* __restrict__ W0,
                                                const float* __restrict__ W1,
                                                const float* __restrict__ inv,
                                                float* __restrict__ X)
{
  int z = blockIdx.y;
  const float* W = z ? W1 : W0;
  int i = blockIdx.x*256 + threadIdx.x;
  X[(long)z*147456 + i] = W[i]*inv[z];
}

// ---------------- host-side orchestration ----------------
extern "C" void kernel_launch(void* const* d_in, const int* in_sizes, int n_in,
                              void* d_out, int out_size, void* d_ws, size_t ws_size,
                              hipStream_t stream)
{
  const float* x      = (const float*)d_in[0];
  const float* Wq     = (const float*)d_in[1];
  const float* Wk     = (const float*)d_in[2];
  const float* Wv     = (const float*)d_in[3];
  const float* Wp     = (const float*)d_in[4];
  const float* bp     = (const float*)d_in[5];
  const float* scale1 = (const float*)d_in[6];
  const float* scale2 = (const float*)d_in[7];
  const float* W1     = (const float*)d_in[8];
  const float* b1     = (const float*)d_in[9];
  const float* W2     = (const float*)d_in[10];
  const float* b2     = (const float*)d_in[11];
  const float* Wo_in  = (const float*)d_in[12];
  const float* Wo_out = (const float*)d_in[13];

  // ---- workspace layout (~248 MiB peak) ----
  char* ws = (char*)d_ws;
  float* xb0 = (float*)(ws + 0);              // NS ping-pong (2 x 384x384 fp32, z-batched)
  float* xb1 = (float*)(ws + 1179648L);
  float* gb  = (float*)(ws + 2359296L);
  float* inv = (float*)(ws + 3538944L);
  u16* WqT = (u16*)(ws + 4194304L);           // bf16 transposed weights [N][K]
  u16* WkT = (u16*)(ws + 4489216L);
  u16* WvT = (u16*)(ws + 4784128L);
  u16* WpT = (u16*)(ws + 5079040L);
  u16* W1T = (u16*)(ws + 5373952L);           // [307][384]
  u16* W2T = (u16*)(ws + 5609728L);           // [384][320] (k-padded with zeros)
  u16* QT  = (u16*)(ws + 5855488L);           // orth(Wo_in)^T, orth(Wo_out)^T bf16
  // five 48MB bf16 activation slots with liveness-based reuse
  u16* h1b = (u16*)(ws + 8388608L);           // S0: h1 -> h6
  u16* qb  = (u16*)(ws + 58720256L);          // S1: q  -> h2
  u16* kb  = (u16*)(ws + 109051904L);         // S2: k  -> h3
  u16* vb  = (u16*)(ws + 159383552L);         // S3: v  -> h4
  u16* atb = (u16*)(ws + 209715200L);         // S4: attn_cat -> h5 [65536][320]
  u16* h2b = qb; u16* h3b = kb; u16* h4b = vb; u16* h5b = atb; u16* h6b = h1b;

  // --- weight transpose+cast (independent of everything else) ---
  tcast_k<<<dim3(12, 2,6),256,0,stream>>>(Wq,24576L, WqT,24576L, 384, 64,384);
  tcast_k<<<dim3(12, 2,6),256,0,stream>>>(Wk,24576L, WkT,24576L, 384, 64,384);
  tcast_k<<<dim3(12, 2,6),256,0,stream>>>(Wv,24576L, WvT,24576L, 384, 64,384);
  tcast_k<<<dim3(12,12,1),256,0,stream>>>(Wp,0L,     WpT,0L,     384,384,384);
  tcast_k<<<dim3(12,10,1),256,0,stream>>>(W1,0L,     W1T,0L,     384,307,384);
  tcast_k<<<dim3(10,12,1),256,0,stream>>>(W2,0L,     W2T,0L,     307,384,320);

  // --- orth via Newton-Schulz polar iteration (fp32, unchanged) ---
  fnorm_k<<<2,256,0,stream>>>(Wo_in, Wo_out, inv);
  nsinit_k<<<dim3(576,2),256,0,stream>>>(Wo_in, Wo_out, inv, xb0);
  float* xa = xb0; float* xb = xb1;
  for(int it=0; it<40; ++it){
    gram_k<<<dim3(6,6,2),256,0,stream>>>(xa, 147456L, gb, 147456L);
    gemm_k<float,float,float,float><<<dim3(6,6,2),256,0,stream>>>(
        xa, 384, 147456L,  gb, 384, 147456L,
        xb, 147456L, 98304L, 384,
        xa, 147456L, nullptr,
        384, 384, 384, -0.5f, 1.5f, 0);
    float* t = xa; xa = xb; xb = t;
  }
  tcast_k<<<dim3(12,12,2),256,0,stream>>>(xa,147456L, QT,147456L, 384,384,384);

  // --- main path: bf16 activations + MFMA throughout, fp32 accumulation ---
  rms_k<float,u16><<<16384,256,0,stream>>>(x, scale1, h1b);
  // QKV: h1[65536,384] @ W*T[h][64,384]^T -> bf16 [B,H,T,64]
  mgemm_k<u16,float><<<dim3(512,1,6),256,0,stream>>>(
      h1b,384,0L,  WqT,384,24576L,
      qb,16384L,98304L,64,  (const float*)nullptr,0L, nullptr,
      65536,64,64,384, 0.f,0);
  mgemm_k<u16,float><<<dim3(512,1,6),256,0,stream>>>(
      h1b,384,0L,  WkT,384,24576L,
      kb,16384L,98304L,64,  (const float*)nullptr,0L, nullptr,
      65536,64,64,384, 0.f,0);
  mgemm_k<u16,float><<<dim3(512,1,6),256,0,stream>>>(
      h1b,384,0L,  WvT,384,24576L,
      vb,16384L,98304L,64,  (const float*)nullptr,0L, nullptr,
      65536,64,64,384, 0.f,0);
  mattn_k<<<1536,256,0,stream>>>(qb,kb,vb,atb);
  // h2 = attn@Wp + bp + h1
  mgemm_k<u16,u16><<<dim3(512,6,1),256,0,stream>>>(
      atb,384,0L,  WpT,384,0L,
      h2b,0L,98304L,384,  h1b,0L, bp,
      65536,384,384,384, 1.f,0);
  rms_k<u16,u16><<<16384,256,0,stream>>>(h2b, scale2, h3b);
  // h4 = h3 @ orth(Wo_in)
  mgemm_k<u16,float><<<dim3(512,6,1),256,0,stream>>>(
      h3b,384,0L,  QT,384,0L,
      h4b,0L,98304L,384,  (const float*)nullptr,0L, nullptr,
      65536,384,384,384, 0.f,0);
  // h5 = relu(h4@W1 + b1), N=307 stored with stride 320, cols 307..319 zeroed
  mgemm_k<u16,float><<<dim3(512,5,1),256,0,stream>>>(
      h4b,384,0L,  W1T,384,0L,
      h5b,0L,81920L,320,  (const float*)nullptr,0L, b1,
      65536,307,320,384, 0.f,1);
  // h6 = h5@W2 + b2  (K padded to 320; pads are zero on both sides)
  mgemm_k<u16,float><<<dim3(512,6,1),256,0,stream>>>(
      h5b,320,0L,  W2T,320,0L,
      h6b,0L,98304L,384,  (const float*)nullptr,0L, b2,
      65536,384,384,320, 0.f,0);
  // out = h6 @ orth(Wo_out) + h6 -> fp32 d_out
  mgemm_k<float,u16><<<dim3(512,6,1),256,0,stream>>>(
      h6b,384,0L,  QT+147456,384,0L,
      (float*)d_out,0L,98304L,384,  h6b,0L, nullptr,
      65536,384,384,384, 1.f,0);

  (void)in_sizes; (void)n_in; (void)ws_size; (void)out_size;
}

// Round 2
// 2086.765 us; speedup vs baseline: 3.5337x; 1.8703x over previous
//
#include <hip/hip_runtime.h>
#include <hip/hip_cooperative_groups.h>

namespace cg = cooperative_groups;

typedef unsigned short u16;
typedef unsigned int   u32;
typedef short s16x8 __attribute__((ext_vector_type(8)));   // 8 bf16 lanes for MFMA
typedef float f32x4 __attribute__((ext_vector_type(4)));

// ---- bf16 helpers (store with round-to-nearest-even) ----
static __device__ __forceinline__ float bf2f(u16 v){ return __uint_as_float(((u32)v)<<16); }
static __device__ __forceinline__ u16 f2bf(float f){
  u32 u = __float_as_uint(f);
  u32 r = (u + 0x7fffu + ((u>>16)&1u)) >> 16;
  return (u16)r;
}
static __device__ __forceinline__ float cvt(float v){ return v; }
static __device__ __forceinline__ float cvt(u16 v){ return bf2f(v); }
static __device__ __forceinline__ void stv(float* p, float v){ *p = v; }
static __device__ __forceinline__ void stv(u16* p, float v){ *p = f2bf(v); }

static __device__ __forceinline__ void ld2(const float* p, float& a, float& b){
  float2 t = *(const float2*)p; a=t.x; b=t.y;
}
static __device__ __forceinline__ void ld2(const u16* p, float& a, float& b){
  u32 t = *(const u32*)p; a = __uint_as_float(t<<16); b = __uint_as_float(t & 0xffff0000u);
}
static __device__ __forceinline__ void st2(float* p, float a, float b){
  float2 t; t.x=a; t.y=b; *(float2*)p = t;
}
static __device__ __forceinline__ void st2(u16* p, float a, float b){
  *(u32*)p = ((u32)f2bf(a)) | (((u32)f2bf(b))<<16);
}

// ---------------- RMSNorm: O = X / rms(X) * scale, vectorized 2-wide ----------------
template<typename TI, typename TO>
__global__ __launch_bounds__(256) void rms_k(const TI* __restrict__ X,
                                             const float* __restrict__ scale,
                                             TO* __restrict__ O)
{
  int row = blockIdx.x*4 + (threadIdx.x>>6);
  int lane = threadIdx.x&63;
  const TI* xr = X + (size_t)row*384;
  float v[6]; float ss = 0.f;
#pragma unroll
  for(int i=0;i<3;i++){
    ld2(xr + 2*lane + 128*i, v[2*i], v[2*i+1]);
    ss += v[2*i]*v[2*i] + v[2*i+1]*v[2*i+1];
  }
#pragma unroll
  for(int off=32; off>0; off>>=1) ss += __shfl_down(ss, off, 64);
  ss = __shfl(ss, 0, 64);
  float r = rsqrtf(ss*(1.0f/384.0f)+1e-6f);
  TO* orow = O + (size_t)row*384;
#pragma unroll
  for(int i=0;i<3;i++){
    int c = 2*lane + 128*i;
    st2(orow + c, v[2*i]*r*scale[c], v[2*i+1]*r*scale[c+1]);
  }
}

// ---------------- transpose + cast fp32 -> bf16: Out[c][r] = (r<Rr ? In[r][c] : 0) ----------------
__global__ __launch_bounds__(256) void tcast_k(const float* __restrict__ In, long isz,
                                               u16* __restrict__ Out, long osz,
                                               int Rr, int Cc, int ldo)
{
  __shared__ float t[32][33];
  const int z = blockIdx.z;
  const float* I = In + (long)z*isz;
  u16* Oz = Out + (long)z*osz;
  const int r0 = blockIdx.x*32, c0 = blockIdx.y*32;
  const int tx = threadIdx.x&31, ty = threadIdx.x>>5;
#pragma unroll
  for(int rr=ty; rr<32; rr+=8){
    int r = r0+rr, c = c0+tx;
    t[rr][tx] = (r<Rr && c<Cc) ? I[(size_t)r*Cc + c] : 0.f;
  }
  __syncthreads();
#pragma unroll
  for(int cc=ty; cc<32; cc+=8){
    int c = c0+cc, r = r0+tx;
    if(c<Cc && r<ldo) Oz[(size_t)c*ldo + r] = f2bf(t[tx][cc]);
  }
}

// ---------------- bf16 MFMA GEMM: C = A[M,K] @ Bt[N,K]^T (+ beta*R + bias, relu) ----------------
// 128x64 tile, BK=32, 4 waves (2x2), 16x16x32 bf16 MFMA, fp32 accum.
// LDS rows padded to 40 u16 (80 B = 5x16B) -> conflict-free ds_read_b128 fragments.
// C/R offset = (m>>8)*cs_hi + (m&255)*cs_lo + z*{csz,rsz} + n  (handles QKV scatter)
// n in [N,Nstore) writes zeros (used to zero-pad h5 columns 307..319).
template<typename TC, typename TR>
__global__ __launch_bounds__(256,4) void mgemm_k(
    const u16* __restrict__ A, int lda, long asz,
    const u16* __restrict__ Bt, int ldb, long bsz,
    TC* __restrict__ C, long csz, long cs_hi, int cs_lo,
    const TR* __restrict__ R, long rsz,
    const float* __restrict__ bias,
    int M, int N, int Nstore, int K, float beta, int relu)
{
  __shared__ __align__(16) u16 As[128*40];
  __shared__ __align__(16) u16 Bs[64*40];
  const int z = blockIdx.z;
  const u16* Az = A + (long)z*asz;
  const u16* Bz = Bt + (long)z*bsz;
  const int m0 = blockIdx.x*128, n0 = blockIdx.y*64;
  const int tid = threadIdx.x;
  const int w = tid>>6, lane = tid&63;
  const int g4 = lane>>4, l16 = lane&15;
  const int wr = w>>1, wc = w&1;
  const int arow = tid>>2, akc = (tid&3)*8;

  const u16* gA0 = Az + (size_t)(m0+arow)*lda + akc;
  const u16* gA1 = Az + (size_t)(m0+64+arow)*lda + akc;
  const bool bok = (n0 + arow) < N;
  const u16* gB  = Bz + (size_t)(bok ? (n0+arow) : 0)*ldb + akc;
  uint4* dA0 = (uint4*)&As[arow*40 + akc];
  uint4* dA1 = (uint4*)&As[(64+arow)*40 + akc];
  uint4* dB  = (uint4*)&Bs[arow*40 + akc];
  if(!bok){ *dB = make_uint4(0,0,0,0); }

  f32x4 fz = {0.f,0.f,0.f,0.f};
  f32x4 acc[4][2];
#pragma unroll
  for(int i=0;i<4;i++)
#pragma unroll
    for(int j=0;j<2;j++) acc[i][j]=fz;

  for(int k0=0;k0<K;k0+=32){
    *dA0 = *(const uint4*)gA0;  gA0 += 32;
    *dA1 = *(const uint4*)gA1;  gA1 += 32;
    if(bok){ *dB = *(const uint4*)gB; gB += 32; }
    __syncthreads();
    s16x8 av[4], bv[2];
#pragma unroll
    for(int mf=0;mf<4;mf++)
      av[mf] = *(const s16x8*)&As[(wr*64 + mf*16 + l16)*40 + g4*8];
#pragma unroll
    for(int nf=0;nf<2;nf++)
      bv[nf] = *(const s16x8*)&Bs[(wc*32 + nf*16 + l16)*40 + g4*8];
#pragma unroll
    for(int mf=0;mf<4;mf++)
#pragma unroll
      for(int nf=0;nf<2;nf++)
        acc[mf][nf] = __builtin_amdgcn_mfma_f32_16x16x32_bf16(av[mf], bv[nf], acc[mf][nf], 0,0,0);
    __syncthreads();
  }
  // epilogue: D layout col=lane&15, row=(lane>>4)*4+i
#pragma unroll
  for(int mf=0;mf<4;mf++)
#pragma unroll
    for(int i=0;i<4;i++){
      int m = m0 + wr*64 + mf*16 + g4*4 + i;
      long rowoff = (long)(m>>8)*cs_hi + (long)(m&255)*cs_lo;
#pragma unroll
      for(int nf=0;nf<2;nf++){
        int n = n0 + wc*32 + nf*16 + l16;
        if(n < Nstore){
          float v = 0.f;
          if(n < N){
            v = acc[mf][nf][i];
            if(R)    v += beta*cvt(R[rowoff + (long)z*rsz + n]);
            if(bias) v += bias[n];
            if(relu) v  = fmaxf(v, 0.f);
          }
          stv(C + (long)z*csz + rowoff + n, v);
        }
      }
    }
}

// ---------------- MFMA causal flash attention: one block per (b,h), T=256, HS=64 ----------------
// QKV packed [B,H,{q,k,v},T,64] bf16: Qb = QKV + bh*49152, K at +16384, V at +32768.
__global__ __launch_bounds__(256,2) void mattn_k(const u16* __restrict__ QKV,
                                                 u16* __restrict__ O)
{
  __shared__ __align__(16) u16 Ks[64*64];    // [s][d], byte = s*128+2d ^ ((s&7)<<4)
  __shared__ __align__(16) u16 Vts[64*64];   // [d][s], byte = d*128+2s ^ ((d&7)<<4)
  __shared__ __align__(16) u16 Ps[4*4096];   // per-wave [m][s], byte = m*128+2s ^ ((m&7)<<4)
  const int bh = blockIdx.x;
  const int b = bh/6, h = bh - b*6;
  const u16* Qb = QKV + (size_t)bh*49152;
  const u16* Kb = Qb + 16384;
  const u16* Vb = Qb + 32768;
  const int tid = threadIdx.x;
  const int w = tid>>6, lane = tid&63;
  const int g4 = lane>>4, l16 = lane&15;
  char* PB = (char*)&Ps[w*4096];
  const int swz = (l16&7)<<4;

  // Q fragments (B-operand): lane holds Q[m=l16+16mi][d=ks*32+g4*8+j]
  s16x8 qf[4][2];
#pragma unroll
  for(int mi=0;mi<4;mi++)
#pragma unroll
    for(int ks=0;ks<2;ks++)
      qf[mi][ks] = *(const s16x8*)(Qb + (size_t)(w*64 + mi*16 + l16)*64 + ks*32 + g4*8);

  f32x4 fzv = {0.f,0.f,0.f,0.f};
  f32x4 o[4][4];
#pragma unroll
  for(int mf=0;mf<4;mf++)
#pragma unroll
    for(int df=0;df<4;df++) o[mf][df]=fzv;
  float mrun[4], lrun[4];
#pragma unroll
  for(int mi=0;mi<4;mi++){ mrun[mi]=-1e30f; lrun[mi]=0.f; }

  for(int st=0; st<4; ++st){
    if(st) __syncthreads();            // previous tile fully consumed before restage
    // stage K tile (coalesced 16B, b128 LDS writes)
#pragma unroll
    for(int it=0; it<2; ++it){
      int c = tid + 256*it;
      int s = c>>3, d0 = (c&7)*8;
      uint4 ld = *(const uint4*)(Kb + (size_t)(st*64+s)*64 + d0);
      int byte = s*128 + d0*2; byte ^= (s&7)<<4;
      *(uint4*)((char*)Ks + byte) = ld;
    }
    // stage V^T tile
#pragma unroll
    for(int it=0; it<2; ++it){
      int c = tid + 256*it;
      int s = c&63, d0 = (c>>6)*8;
      uint4 ld = *(const uint4*)(Vb + (size_t)(st*64+s)*64 + d0);
#pragma unroll
      for(int jj=0; jj<4; ++jj){
        u32 ww = (jj==0)?ld.x:(jj==1)?ld.y:(jj==2)?ld.z:ld.w;
        int d = d0 + 2*jj;
        int byte0 = d*128 + s*2;     byte0 ^= (d&7)<<4;
        int byte1 = (d+1)*128 + s*2; byte1 ^= ((d+1)&7)<<4;
        *(u16*)((char*)Vts + byte0) = (u16)(ww & 0xffffu);
        *(u16*)((char*)Vts + byte1) = (u16)(ww >> 16);
      }
    }
    __syncthreads();
    if(w < st) continue;               // wave-uniform causal tile skip

    // S^T = K . Q^T : D[s][m], frags sc[sf][mi]
    f32x4 sc[4][4];
#pragma unroll
    for(int sf=0; sf<4; ++sf){
      int row = sf*16 + l16;
      s16x8 kf0 = *(const s16x8*)((char*)Ks + ((row*128 + g4*16) ^ swz));
      s16x8 kf1 = *(const s16x8*)((char*)Ks + ((row*128 + 64 + g4*16) ^ swz));
#pragma unroll
      for(int mi=0; mi<4; ++mi){
        f32x4 t = __builtin_amdgcn_mfma_f32_16x16x32_bf16(kf0, qf[mi][0], fzv, 0,0,0);
        sc[sf][mi] = __builtin_amdgcn_mfma_f32_16x16x32_bf16(kf1, qf[mi][1], t, 0,0,0);
      }
    }
    // online softmax per row m = mi*16+l16
    float alpha[4];
#pragma unroll
    for(int mi=0; mi<4; ++mi){
      int mloc = mi*16 + l16;
      float rmax = -3.0e38f;
#pragma unroll
      for(int sf=0; sf<4; ++sf)
#pragma unroll
        for(int i=0;i<4;i++){
          float vv = sc[sf][mi][i]*0.125f;
          if(st==w && (sf*16 + g4*4 + i) > mloc) vv = -1e30f;
          sc[sf][mi][i] = vv;
          rmax = fmaxf(rmax, vv);
        }
      rmax = fmaxf(rmax, __shfl_xor(rmax, 16, 64));
      rmax = fmaxf(rmax, __shfl_xor(rmax, 32, 64));
      float mnew = fmaxf(mrun[mi], rmax);
      float al = __expf(mrun[mi] - mnew);
      mrun[mi] = mnew;
      float ls = 0.f;
#pragma unroll
      for(int sf=0; sf<4; ++sf){
        float p0 = __expf(sc[sf][mi][0]-mnew);
        float p1 = __expf(sc[sf][mi][1]-mnew);
        float p2 = __expf(sc[sf][mi][2]-mnew);
        float p3 = __expf(sc[sf][mi][3]-mnew);
        ls += p0+p1+p2+p3;
        ushort4 pk; pk.x=f2bf(p0); pk.y=f2bf(p1); pk.z=f2bf(p2); pk.w=f2bf(p3);
        int byte = mloc*128 + sf*32 + g4*8; byte ^= (l16&7)<<4;
        *(ushort4*)(PB + byte) = pk;
      }
      ls += __shfl_xor(ls, 16, 64);
      ls += __shfl_xor(ls, 32, 64);
      lrun[mi] = lrun[mi]*al + ls;
      alpha[mi] = al;
    }
    // rescale O
#pragma unroll
    for(int mf=0; mf<4; ++mf)
#pragma unroll
      for(int i=0;i<4;i++){
        float at = __shfl(alpha[mf], g4*4 + i, 64);
#pragma unroll
        for(int df=0; df<4; ++df) o[mf][df][i] *= at;
      }
    // PV: O[m][d] += P[m][s] V[s][d]
    s16x8 vbf[4][2];
#pragma unroll
    for(int df=0; df<4; ++df){
      int row = df*16 + l16;
      vbf[df][0] = *(const s16x8*)((char*)Vts + ((row*128 + g4*16) ^ swz));
      vbf[df][1] = *(const s16x8*)((char*)Vts + ((row*128 + 64 + g4*16) ^ swz));
    }
#pragma unroll
    for(int mf=0; mf<4; ++mf){
      int row = mf*16 + l16;
      s16x8 pa0 = *(const s16x8*)(PB + ((row*128 + g4*16) ^ swz));
      s16x8 pa1 = *(const s16x8*)(PB + ((row*128 + 64 + g4*16) ^ swz));
#pragma unroll
      for(int df=0; df<4; ++df){
        f32x4 t = __builtin_amdgcn_mfma_f32_16x16x32_bf16(pa0, vbf[df][0], o[mf][df], 0,0,0);
        o[mf][df] = __builtin_amdgcn_mfma_f32_16x16x32_bf16(pa1, vbf[df][1], t, 0,0,0);
      }
    }
  }
  // normalize + store bf16 to attn_cat[b][t][h*64+d]
#pragma unroll
  for(int mf=0; mf<4; ++mf)
#pragma unroll
    for(int i=0;i<4;i++){
      float lt = __shfl(lrun[mf], g4*4 + i, 64);
      float rl = 1.f/lt;
      u16* orow = O + ((size_t)(b*256 + w*64 + mf*16 + g4*4 + i))*384 + h*64;
#pragma unroll
      for(int df=0; df<4; ++df)
        orow[df*16 + l16] = f2bf(o[mf][df][i]*rl);
    }
}

// ---------------- cooperative Newton-Schulz polar orthogonalization ----------------
// One launch replaces fnorm+nsinit+80 small GEMM launches. 72 blocks = 6x6 tiles x 2 z.
// 9 quintic iterations (Muon coeffs) + 6 cubic polish, fp32.  Final Q^T cast to bf16.
static __device__ __forceinline__ void tile_mm384(const float* __restrict__ P,
                                                  const float* __restrict__ Q,
                                                  int i0, int j0, bool ptrans,
                                                  float acc[4][4])
{
  __shared__ __align__(16) float As[16][68];
  __shared__ __align__(16) float Bs[16][68];
  const int tid = threadIdx.x;
  const int tm = tid>>4, tn = tid&15;
#pragma unroll
  for(int i=0;i<4;i++)
#pragma unroll
    for(int j=0;j<4;j++) acc[i][j]=0.f;
  for(int c0=0;c0<384;c0+=16){
    __syncthreads();
    if(ptrans){
      const int lr=tid>>6, lc=tid&63;
#pragma unroll
      for(int i=0;i<4;i++){
        int c = c0 + lr + 4*i;
        As[lr+4*i][lc] = P[(size_t)c*384 + i0+lc];
        Bs[lr+4*i][lc] = Q[(size_t)c*384 + j0+lc];
      }
    } else {
      const int la_m=tid>>4, la_k=tid&15;
#pragma unroll
      for(int i=0;i<4;i++)
        As[la_k][la_m+16*i] = P[(size_t)(i0+la_m+16*i)*384 + c0+la_k];
      const int lb_k=tid>>6, lb_n=tid&63;
#pragma unroll
      for(int i=0;i<4;i++)
        Bs[lb_k+4*i][lb_n] = Q[(size_t)(c0+lb_k+4*i)*384 + j0+lb_n];
    }
    __syncthreads();
#pragma unroll
    for(int kk=0;kk<16;kk++){
      float4 av = *(const float4*)&As[kk][tm*4];
      float4 bv = *(const float4*)&Bs[kk][tn*4];
      acc[0][0]+=av.x*bv.x; acc[0][1]+=av.x*bv.y; acc[0][2]+=av.x*bv.z; acc[0][3]+=av.x*bv.w;
      acc[1][0]+=av.y*bv.x; acc[1][1]+=av.y*bv.y; acc[1][2]+=av.y*bv.z; acc[1][3]+=av.y*bv.w;
      acc[2][0]+=av.z*bv.x; acc[2][1]+=av.z*bv.y; acc[2][2]+=av.z*bv.z; acc[2][3]+=av.z*bv.w;
      acc[3][0]+=av.w*bv.x; acc[3][1]+=av.w*bv.y; acc[3][2]+=av.w*bv.z; acc[3][3]+=av.w*bv.w;
    }
  }
  __syncthreads();
}

__global__ __launch_bounds__(256,1) void ns_k(const float* __restrict__ W0,
                                              const float* __restrict__ W1,
                                              float* __restrict__ X0,
                                              float* __restrict__ X1,
                                              float* __restrict__ Gb,
                                              float* __restrict__ Mb,
                                              float* __restrict__ part,
                                              u16* __restrict__ QT)
{
  cg::grid_group grid = cg::this_grid();
  const int blk = blockIdx.x;
  const int z = blk/36, t = blk%36;
  const int i0 = (t%6)*64, j0 = (t/6)*64;
  const int tid = threadIdx.x;
  const int tm = tid>>4, tn = tid&15;
  const float* W = z ? W1 : W0;
  float* Xa = X0 + (size_t)z*147456;
  float* Xb = X1 + (size_t)z*147456;
  float* G  = Gb + (size_t)z*147456;
  float* M  = Mb + (size_t)z*147456;

  // --- Frobenius norm partials ---
  {
    float s = 0.f;
    for(int i=t*4096+tid; i<(t+1)*4096; i+=256){ float v=W[i]; s+=v*v; }
    __shared__ float red[256];
    red[tid]=s; __syncthreads();
    for(int off=128;off>0;off>>=1){ if(tid<off) red[tid]+=red[tid+off]; __syncthreads(); }
    if(tid==0) part[blk]=red[0];
  }
  grid.sync();
  // --- init X = W / ||W||_F  (sigma_max <= 1) ---
  {
    float a=0.f;
#pragma unroll 4
    for(int i=0;i<36;i++) a += part[z*36+i];
    float inv = rsqrtf(a);
    for(int idx=tid; idx<4096; idx+=256){
      int r=idx>>6, c=idx&63;
      size_t o = (size_t)(i0+r)*384 + j0+c;
      Xa[o] = W[o]*inv;
    }
  }
  grid.sync();

  float acc[4][4];
  // --- 9 quintic iterations: X <- X(aI + bG + cG^2), G = X^T X ---
  for(int it=0; it<9; ++it){
    tile_mm384(Xa, Xa, i0, j0, true, acc);
#pragma unroll
    for(int i=0;i<4;i++)
#pragma unroll
      for(int j=0;j<4;j++)
        G[(size_t)(i0+tm*4+i)*384 + j0+tn*4+j] = acc[i][j];
    grid.sync();
    tile_mm384(G, G, i0, j0, false, acc);
#pragma unroll
    for(int i=0;i<4;i++)
#pragma unroll
      for(int j=0;j<4;j++){
        int m=i0+tm*4+i, n=j0+tn*4+j;
        float v = 2.0315f*acc[i][j] - 4.7750f*G[(size_t)m*384+n] + (m==n ? 3.4445f : 0.f);
        M[(size_t)m*384+n] = v;
      }
    grid.sync();
    tile_mm384(Xa, M, i0, j0, false, acc);
#pragma unroll
    for(int i=0;i<4;i++)
#pragma unroll
      for(int j=0;j<4;j++)
        Xb[(size_t)(i0+tm*4+i)*384 + j0+tn*4+j] = acc[i][j];
    { float* tp=Xa; Xa=Xb; Xb=tp; }
    grid.sync();
  }
  // --- 6 cubic polish iterations: X <- 1.5X - 0.5 X G ---
  for(int it=0; it<6; ++it){
    tile_mm384(Xa, Xa, i0, j0, true, acc);
#pragma unroll
    for(int i=0;i<4;i++)
#pragma unroll
      for(int j=0;j<4;j++)
        G[(size_t)(i0+tm*4+i)*384 + j0+tn*4+j] = acc[i][j];
    grid.sync();
    tile_mm384(Xa, G, i0, j0, false, acc);
#pragma unroll
    for(int i=0;i<4;i++)
#pragma unroll
      for(int j=0;j<4;j++){
        size_t o = (size_t)(i0+tm*4+i)*384 + j0+tn*4+j;
        Xb[o] = 1.5f*Xa[o] - 0.5f*acc[i][j];
      }
    { float* tp=Xa; Xa=Xb; Xb=tp; }
    grid.sync();
  }
  // --- write Q^T bf16: QT[z][col][row] = Q[row][col] ---
  for(int idx=tid; idx<4096; idx+=256){
    int r=idx>>6, c=idx&63;
    QT[(size_t)z*147456 + (size_t)(j0+c)*384 + (i0+r)] =
        f2bf(Xa[(size_t)(i0+r)*384 + j0+c]);
  }
}

// ---------------- host-side orchestration ----------------
extern "C" void kernel_launch(void* const* d_in, const int* in_sizes, int n_in,
                              void* d_out, int out_size, void* d_ws, size_t ws_size,
                              hipStream_t stream)
{
  const float* x      = (const float*)d_in[0];
  const float* Wq     = (const float*)d_in[1];
  const float* Wk     = (const float*)d_in[2];
  const float* Wv     = (const float*)d_in[3];
  const float* Wp     = (const float*)d_in[4];
  const float* bp     = (const float*)d_in[5];
  const float* scale1 = (const float*)d_in[6];
  const float* scale2 = (const float*)d_in[7];
  const float* W1     = (const float*)d_in[8];
  const float* b1     = (const float*)d_in[9];
  const float* W2     = (const float*)d_in[10];
  const float* b2     = (const float*)d_in[11];
  const float* Wo_in  = (const float*)d_in[12];
  const float* Wo_out = (const float*)d_in[13];

  // ---- workspace layout (~252 MiB peak) ----
  char* ws = (char*)d_ws;
  float* xb0  = (float*)(ws + 0);             // NS ping-pong (2 x 384x384 fp32, z-batched)
  float* xb1  = (float*)(ws + 1179648L);
  float* gbuf = (float*)(ws + 2359296L);
  float* mbuf = (float*)(ws + 3538944L);
  float* part = (float*)(ws + 4718592L);      // 72 floats
  u16* Wqkv = (u16*)(ws + 4719104L);          // [h][{q,k,v}][64][384] bf16, 884736 B
  u16* WpT  = (u16*)(ws + 5603840L);          // [384][384]
  u16* W1T  = (u16*)(ws + 5898752L);          // [307][384]
  u16* W2T  = (u16*)(ws + 6134528L);          // [384][320] (k-padded with zeros)
  u16* QT   = (u16*)(ws + 6380288L);          // orth(Wo_in)^T, orth(Wo_out)^T bf16
  u16* h1b  = (u16*)(ws + 8388608L);          // S0: h1 -> h6                (48 MB)
  u16* qkvb = (u16*)(ws + 58720256L);         // S1-S3: qkv packed -> h2/h3/h4 (144 MB)
  u16* atb  = (u16*)(ws + 209715200L);        // S4: attn_cat -> h5 [65536][320]
  u16* h2b = qkvb;
  u16* h3b = qkvb + 25165824L;
  u16* h4b = qkvb + 50331648L;
  u16* h5b = atb;
  u16* h6b = h1b;

  // --- weight transpose+cast (independent of everything else) ---
  tcast_k<<<dim3(12, 2,6),256,0,stream>>>(Wq,24576L, Wqkv,        73728L, 384, 64,384);
  tcast_k<<<dim3(12, 2,6),256,0,stream>>>(Wk,24576L, Wqkv+24576L, 73728L, 384, 64,384);
  tcast_k<<<dim3(12, 2,6),256,0,stream>>>(Wv,24576L, Wqkv+49152L, 73728L, 384, 64,384);
  tcast_k<<<dim3(12,12,1),256,0,stream>>>(Wp,0L,     WpT,0L,     384,384,384);
  tcast_k<<<dim3(12,10,1),256,0,stream>>>(W1,0L,     W1T,0L,     384,307,384);
  tcast_k<<<dim3(10,12,1),256,0,stream>>>(W2,0L,     W2T,0L,     307,384,320);

  // --- orth via single cooperative Newton-Schulz kernel ---
  {
    const float* a0 = Wo_in; const float* a1 = Wo_out;
    float* p0 = xb0; float* p1 = xb1; float* pg = gbuf; float* pm = mbuf;
    float* pp = part; u16* pq = QT;
    void* nsargs[] = { (void*)&a0, (void*)&a1, (void*)&p0, (void*)&p1,
                       (void*)&pg, (void*)&pm, (void*)&pp, (void*)&pq };
    hipLaunchCooperativeKernel((const void*)&ns_k, dim3(72), dim3(256),
                               nsargs, 0u, stream);
  }

  // --- main path: bf16 activations + MFMA throughout, fp32 accumulation ---
  rms_k<float,u16><<<16384,256,0,stream>>>(x, scale1, h1b);
  // QKV in ONE launch: z = h*3+j, out [B,H,3,T,64]
  mgemm_k<u16,float><<<dim3(512,1,18),256,0,stream>>>(
      h1b,384,0L,  Wqkv,384,24576L,
      qkvb,16384L,294912L,64,  (const float*)nullptr,0L, nullptr,
      65536,64,64,384, 0.f,0);
  mattn_k<<<1536,256,0,stream>>>(qkvb, atb);
  // h2 = attn@Wp + bp + h1
  mgemm_k<u16,u16><<<dim3(512,6,1),256,0,stream>>>(
      atb,384,0L,  WpT,384,0L,
      h2b,0L,98304L,384,  h1b,0L, bp,
      65536,384,384,384, 1.f,0);
  rms_k<u16,u16><<<16384,256,0,stream>>>(h2b, scale2, h3b);
  // h4 = h3 @ orth(Wo_in)
  mgemm_k<u16,float><<<dim3(512,6,1),256,0,stream>>>(
      h3b,384,0L,  QT,384,0L,
      h4b,0L,98304L,384,  (const float*)nullptr,0L, nullptr,
      65536,384,384,384, 0.f,0);
  // h5 = relu(h4@W1 + b1), N=307 stored with stride 320, cols 307..319 zeroed
  mgemm_k<u16,float><<<dim3(512,5,1),256,0,stream>>>(
      h4b,384,0L,  W1T,384,0L,
      h5b,0L,81920L,320,  (const float*)nullptr,0L, b1,
      65536,307,320,384, 0.f,1);
  // h6 = h5@W2 + b2  (K padded to 320; pads are zero on both sides)
  mgemm_k<u16,float><<<dim3(512,6,1),256,0,stream>>>(
      h5b,320,0L,  W2T,320,0L,
      h6b,0L,98304L,384,  (const float*)nullptr,0L, b2,
      65536,384,384,320, 0.f,0);
  // out = h6 @ orth(Wo_out) + h6 -> fp32 d_out
  mgemm_k<float,u16><<<dim3(512,6,1),256,0,stream>>>(
      h6b,384,0L,  QT+147456,384,0L,
      (float*)d_out,0L,98304L,384,  h6b,0L, nullptr,
      65536,384,384,384, 1.f,0);

  (void)in_sizes; (void)n_in; (void)ws_size; (void)out_size;
}